// Round 4
// baseline (207.786 us; speedup 1.0000x reference)
//
#include <hip/hip_runtime.h>
#include <hip/hip_bf16.h>
#include <math.h>

// Self_Attention_Local R4: single fused bf16-MFMA attention kernel + coalesced
// convert. Key algebra: (a) instance-norm mu and per-row max/sum all fold out
// of softmax -> P stored unnormalized, normalization via ones-column in the PV
// MFMA (col n=8 accumulates the row sum); (b) map stats computed from 8x8 Gram
// matrices: sum(S) = sQ.sK, sum(S^2) = tr((QQ^T)(KK^T)) -> no score recompute.
// LDS: QKV staging (40KB) overlaid with P/ctx staging (25.6KB) -> 40KB total,
// 4 blocks/CU, grid 1024 = exactly one full-residency round.
// Output GEMM fused: per-block partial (32 rows x 128 cols) atomicAdd into out.

typedef short bfrag __attribute__((ext_vector_type(8)));   // 8 bf16 = 4 VGPRs
typedef float f32x4 __attribute__((ext_vector_type(4)));

static __device__ __forceinline__ short f2bf(float x) {
    __hip_bfloat16 h = __float2bfloat16(x);
    return __builtin_bit_cast(short, h);
}
static __device__ __forceinline__ bfrag bzero() {
    bfrag z;
    #pragma unroll
    for (int j = 0; j < 8; ++j) z[j] = 0;
    return z;
}

// ---- convert: dst-linear (coalesced writes, scattered L2 reads) ----
//  emb_bf[4096][128]; Wp[x][h][i][k] = Wx[k][i*8+h]; Wout_pt[h][col][i] = Wout[i*8+h][col]
__global__ __launch_bounds__(256) void convert2(
    const float* __restrict__ emb, const float* __restrict__ Wq,
    const float* __restrict__ Wk,  const float* __restrict__ Wv,
    const float* __restrict__ Wout,
    short* __restrict__ emb_bf, short* __restrict__ Wp, short* __restrict__ Wout_pt)
{
    const int gid = blockIdx.x * 256 + threadIdx.x;       // 0..1048575
    if (gid < 524288) {
        emb_bf[gid] = f2bf(emb[gid]);
    } else if (gid < 917504) {
        const int g = gid - 524288;
        const int x = g >> 17, r = g & 131071;
        const int h = r >> 14, i = (r >> 7) & 127, k = r & 127;
        const float* W = (x == 0) ? Wq : (x == 1) ? Wk : Wv;
        Wp[g] = f2bf(W[k * 1024 + i * 8 + h]);
    } else {
        const int g = gid - 917504;
        const int h = g >> 14, col = (g >> 7) & 127, i = g & 127;
        Wout_pt[g] = f2bf(Wout[(i * 8 + h) * 128 + col]);
    }
}

// ---- fused attention + output GEMM ----
// LDS overlay (shorts): region A: QT 0 | KT 4096 | QN 8192 | KN 12288 | VS 16384..20480
//                       region B: PS 0 (4 x 16 x 136) | CTX 8704 (4 x 8 x 128)
#define QT  0
#define KT  4096
#define QN  8192
#define KN  12288
#define VS  16384
#define PS  0
#define CTX 8704
#define LDP 136

__global__ __launch_bounds__(256, 4) void attn3(
    const short* __restrict__ emb_bf,   // [4096][128]
    const short* __restrict__ Wp,       // [3][8][128][128]
    const short* __restrict__ Wout_pt,  // [8][128 col][128 i]
    float* __restrict__ out)            // [4096][128] (pre-zeroed, atomicAdd)
{
    __shared__ short lds[20480];        // 40 KB
    const int bid = blockIdx.x;         // 0..1023
    const int pg  = bid >> 3;           // patch group of 4
    const int h   = bid & 7;            // head
    const int t   = threadIdx.x;
    const int w    = t >> 6;            // wave 0..3 (owns patch pl = w)
    const int lane = t & 63;
    const int m16  = lane & 15;
    const int quad = lane >> 4;
    const int q8   = quad * 8;

    // ================= QKV: (32x128) @ W_h (128x128) x3 =================
    {
        bfrag a[2][4];
        #pragma unroll
        for (int tm = 0; tm < 2; ++tm)
            #pragma unroll
            for (int ks = 0; ks < 4; ++ks)
                a[tm][ks] = *(const bfrag*)&emb_bf[(pg*32 + tm*16 + m16)*128 + ks*32 + q8];

        #pragma unroll
        for (int tt = 0; tt < 6; ++tt) {
            const int nt = w * 6 + tt;            // 0..23 = {q,k,v} x 8 i-tiles
            const int x  = nt >> 3;
            const int i0 = (nt & 7) * 16;
            const short* Wb = Wp + ((x*8 + h)*128 + i0 + m16) * 128;
            bfrag b[4];
            #pragma unroll
            for (int ks = 0; ks < 4; ++ks)
                b[ks] = *(const bfrag*)&Wb[ks*32 + q8];
            f32x4 c0 = {0.f,0.f,0.f,0.f}, c1 = {0.f,0.f,0.f,0.f};
            #pragma unroll
            for (int ks = 0; ks < 4; ++ks) {
                c0 = __builtin_amdgcn_mfma_f32_16x16x32_bf16(a[0][ks], b[ks], c0, 0,0,0);
                c1 = __builtin_amdgcn_mfma_f32_16x16x32_bf16(a[1][ks], b[ks], c1, 0,0,0);
            }
            #pragma unroll
            for (int tm = 0; tm < 2; ++tm) {
                const f32x4 cc = tm ? c1 : c0;
                const int mrow0 = tm*16 + quad*4;     // 4 consecutive tokens
                const int pl = mrow0 >> 3;            // local patch
                const int p0 = mrow0 & 7;             // 0 or 4
                const int col = i0 + m16;
                if (x == 0) {
                    short4 v;
                    v.x = f2bf(cc[0]); v.y = f2bf(cc[1]);
                    v.z = f2bf(cc[2]); v.w = f2bf(cc[3]);
                    *(short4*)&lds[QT + pl*1024 + col*8 + p0] = v;   // Qt[i][p]
                    #pragma unroll
                    for (int r = 0; r < 4; ++r)                      // Qn[p][i]
                        lds[QN + pl*1024 + (p0 + r)*128 + col] = f2bf(cc[r]);
                } else if (x == 1) {
                    short4 v;
                    v.x = f2bf(cc[0]); v.y = f2bf(cc[1]);
                    v.z = f2bf(cc[2]); v.w = f2bf(cc[3]);
                    *(short4*)&lds[KT + pl*1024 + col*8 + p0] = v;   // Kt[j][p]
                    #pragma unroll
                    for (int r = 0; r < 4; ++r)                      // Kn[p][j]
                        lds[KN + pl*1024 + (p0 + r)*128 + col] = f2bf(cc[r]);
                } else {
                    #pragma unroll
                    for (int r = 0; r < 4; ++r)                      // Vs[p][j]
                        lds[VS + pl*1024 + (p0 + r)*128 + col] = f2bf(cc[r]);
                }
            }
        }
    }
    __syncthreads();

    // ============ stats via Grams: sum(S)=sQ.sK, sum(S^2)=tr(G H) ============
    float rs2, nbias;
    {
        bfrag gq[4], gk[4], gs[4], ones;
        #pragma unroll
        for (int j = 0; j < 8; ++j) ones[j] = (short)0x3F80;   // bf16 1.0
        #pragma unroll
        for (int ks = 0; ks < 4; ++ks) {
            gq[ks] = (m16 < 8) ? *(const bfrag*)&lds[QN + w*1024 + m16*128 + ks*32 + q8] : bzero();
            gk[ks] = (m16 < 8) ? *(const bfrag*)&lds[KN + w*1024 + m16*128 + ks*32 + q8] : bzero();
            gs[ks] = (m16 < 8) ? *(const bfrag*)&lds[QN + w*1024 + m16*128 + ks*32 + q8]
                               : *(const bfrag*)&lds[KN + w*1024 + (m16 - 8)*128 + ks*32 + q8];
        }
        f32x4 cg = {0.f,0.f,0.f,0.f}, ch = {0.f,0.f,0.f,0.f}, cs = {0.f,0.f,0.f,0.f};
        #pragma unroll
        for (int ks = 0; ks < 4; ++ks) {
            cg = __builtin_amdgcn_mfma_f32_16x16x32_bf16(gq[ks], gq[ks], cg, 0,0,0); // G=QQ^T
            ch = __builtin_amdgcn_mfma_f32_16x16x32_bf16(gk[ks], gk[ks], ch, 0,0,0); // H=KK^T
            cs = __builtin_amdgcn_mfma_f32_16x16x32_bf16(gs[ks], ones,  cs, 0,0,0);  // row sums
        }
        float gh = 0.f, sp = 0.f;
        #pragma unroll
        for (int r = 0; r < 4; ++r) {
            gh = fmaf(cg[r], ch[r], gh);                     // invalid entries are 0
            sp = fmaf(cs[r], __shfl_xor(cs[r], 32), sp);     // sQ[p]*sK[p] pairs
        }
        sp += __shfl_xor(sp, 16);                            // all lanes: sum(S)
        #pragma unroll
        for (int off = 1; off <= 32; off <<= 1)
            gh += __shfl_xor(gh, off);                       // all lanes: sum(S^2)
        const float mean = sp * (1.f / 16384.f);
        const float var  = gh * (1.f / 16384.f) - mean * mean;
        rs2   = rsqrtf(var + 1e-5f) * 1.44269504f;           // fold log2(e)
        nbias = -mean * rs2;
    }

    // ============ hoist all region-A fragments (A dies after barrier) ============
    bfrag as_all[8], bs[8], bv[4];
    #pragma unroll
    for (int mb = 0; mb < 8; ++mb)
        as_all[mb] = (quad == 0) ? *(const bfrag*)&lds[QT + w*1024 + (mb*16 + m16)*8] : bzero();
    #pragma unroll
    for (int nt = 0; nt < 8; ++nt)
        bs[nt] = (quad == 0) ? *(const bfrag*)&lds[KT + w*1024 + (nt*16 + m16)*8] : bzero();
    #pragma unroll
    for (int ks = 0; ks < 4; ++ks) {
        if (m16 < 8)
            bv[ks] = *(const bfrag*)&lds[VS + w*1024 + m16*128 + ks*32 + q8];
        else if (m16 == 8) {                         // ones column -> row sums
            bfrag o; 
            #pragma unroll
            for (int j = 0; j < 8; ++j) o[j] = (short)0x3F80;
            bv[ks] = o;
        } else
            bv[ks] = bzero();
    }
    __syncthreads();   // region A -> region B transition (cross-wave overlap)

    // output-row mapping for this wave's patch
    const int pat = pg*4 + w;
    const int bb = pat >> 5, rem = pat & 31;
    const int dd = rem >> 4, hh2 = (rem >> 2) & 3, ww2 = rem & 3;
    int orow[4];
    #pragma unroll
    for (int r = 0; r < 4; ++r) {
        const int p  = (quad & 1)*4 + r;             // valid for quad<2
        const int p1 = p >> 2, p2 = (p >> 1) & 1, p3 = p & 1;
        orow[r] = bb*256 + ((((dd*2 + p1)*4 + hh2)*2 + p2)*4 + ww2)*2 + p3;
    }

    // ============ 8 bands of 16 score-rows: scores -> exp -> PV ============
    const int psb = PS + w * (16 * LDP);
    #pragma unroll 1
    for (int mb = 0; mb < 8; ++mb) {
        #pragma unroll
        for (int nt = 0; nt < 8; ++nt) {
            f32x4 c = {0.f,0.f,0.f,0.f};
            c = __builtin_amdgcn_mfma_f32_16x16x32_bf16(as_all[mb], bs[nt], c, 0,0,0);
            const int base = psb + (quad*4)*LDP + nt*16 + m16;
            #pragma unroll
            for (int r = 0; r < 4; ++r)
                lds[base + r*LDP] = f2bf(exp2f(fmaf(c[r], rs2, nbias)));
        }
        // PV over full j=128 for these 16 i-rows (ones col gives row sums at n=8)
        f32x4 acc = {0.f,0.f,0.f,0.f};
        #pragma unroll
        for (int ks = 0; ks < 4; ++ks) {
            bfrag ap = *(const bfrag*)&lds[psb + m16*LDP + ks*32 + q8];
            acc = __builtin_amdgcn_mfma_f32_16x16x32_bf16(ap, bv[ks], acc, 0,0,0);
        }
        const int src = (lane & 48) + 8;             // lane holding col p=8 (row sum)
        float s0 = __shfl(acc[0], src), s1 = __shfl(acc[1], src);
        float s2 = __shfl(acc[2], src), s3 = __shfl(acc[3], src);
        if (m16 < 8) {                               // ctx_s[p][i] bf16
            short4 v;
            v.x = f2bf(acc[0] / s0); v.y = f2bf(acc[1] / s1);
            v.z = f2bf(acc[2] / s2); v.w = f2bf(acc[3] / s3);
            *(short4*)&lds[CTX + w*1024 + m16*128 + mb*16 + quad*4] = v;
        }
    }

    // ============ fused out-GEMM: (8x128 ctx) @ Wout_h (128x128), atomicAdd ====
    bfrag ac[4];
    #pragma unroll
    for (int ks = 0; ks < 4; ++ks)
        ac[ks] = (m16 < 8) ? *(const bfrag*)&lds[CTX + w*1024 + m16*128 + ks*32 + q8] : bzero();
    const short* Wo = Wout_pt + h * 16384;
    #pragma unroll 1
    for (int nt = 0; nt < 8; ++nt) {
        f32x4 acc = {0.f,0.f,0.f,0.f};
        #pragma unroll
        for (int ks = 0; ks < 4; ++ks) {
            bfrag wb = *(const bfrag*)&Wo[(nt*16 + m16)*128 + ks*32 + q8];
            acc = __builtin_amdgcn_mfma_f32_16x16x32_bf16(ac[ks], wb, acc, 0,0,0);
        }
        if (quad < 2) {
            #pragma unroll
            for (int r = 0; r < 4; ++r)
                atomicAdd(&out[orow[r]*128 + nt*16 + m16], acc[r]);
        }
    }
}

extern "C" void kernel_launch(void* const* d_in, const int* in_sizes, int n_in,
                              void* d_out, int out_size, void* d_ws, size_t ws_size,
                              hipStream_t stream) {
    const float* emb  = (const float*)d_in[0];   // (512, 8, 128)
    const float* Wq   = (const float*)d_in[1];   // (128, 1024)
    const float* Wk   = (const float*)d_in[2];
    const float* Wv   = (const float*)d_in[3];
    const float* Wout = (const float*)d_in[4];   // (1024, 128)
    float* out = (float*)d_out;                  // 524288 floats

    short* emb_bf  = (short*)d_ws;               // 524288
    short* Wp      = emb_bf + 524288;            // 393216
    short* Wout_pt = Wp + 393216;                // 131072  (total 2 MB)

    convert2<<<4096, 256, 0, stream>>>(emb, Wq, Wk, Wv, Wout, emb_bf, Wp, Wout_pt);
    hipMemsetAsync(out, 0, (size_t)out_size * sizeof(float), stream);
    attn3<<<1024, 256, 0, stream>>>(emb_bf, Wp, Wout_pt, out);
}

// Round 5
// 117.531 us; speedup vs baseline: 1.7679x; 1.7679x over previous
//
#include <hip/hip_runtime.h>
#include <hip/hip_bf16.h>
#include <math.h>

// Self_Attention_Local R5: fused bf16-MFMA attention, no atomics.
//   convertW: Wq/Wk/Wv -> Wp[x][h][i][k] bf16, Wout -> Wout_pt[h][col][i] bf16
//             (LDS-transpose based, coalesced writes)
//   attn4:    block = (patch-group of 4, head). QKV (emb fp32 read + cvt in
//             kernel), Gram-based instance-norm stats, folded softmax
//             (exp2((S-mean)*rs), no row max needed), PV as V*P^T with a
//             ones-row giving row sums, fused per-head out-GEMM -> fp32
//             partials in ws. P buffer XOR-swizzled, single-buffer, manually
//             software-pipelined (next band's scores between P-write and PV).
//   reduce8:  out[orow(pat,p)][col] = sum_h part[h][pat*8+p][col]  (+ permute)

typedef short bfrag __attribute__((ext_vector_type(8)));   // 8 bf16 = 4 VGPRs
typedef float f32x4 __attribute__((ext_vector_type(4)));

static __device__ __forceinline__ short f2bf(float x) {
    __hip_bfloat16 h = __float2bfloat16(x);
    return __builtin_bit_cast(short, h);
}
static __device__ __forceinline__ bfrag bzero() {
    bfrag z;
    #pragma unroll
    for (int j = 0; j < 8; ++j) z[j] = 0;
    return z;
}

// ---------------- convertW: 128 blocks ----------------
// blocks 0..95:  (x, h, k-quarter): Wp[x][h][i][k] = Wx[k][i*8+h]
// blocks 96..127:(h, col-quarter):  Wout_pt[h][col][i] = Wout[i*8+h][col]
__global__ __launch_bounds__(256) void convertW(
    const float* __restrict__ Wq, const float* __restrict__ Wk,
    const float* __restrict__ Wv, const float* __restrict__ Wout,
    short* __restrict__ Wp, short* __restrict__ Wout_pt)
{
    __shared__ short lt[128 * 33];          // union: [32][129] or [128][33]
    const int b = blockIdx.x, t = threadIdx.x;
    if (b < 96) {
        const int x = b >> 5, h = (b >> 2) & 7, k0 = (b & 3) * 32;
        const float* W = (x == 0) ? Wq : (x == 1) ? Wk : Wv;
        #pragma unroll 4
        for (int rr = 0; rr < 16; ++rr) {
            const int k = rr * 2 + (t >> 7);          // 0..31
            const int i = t & 127;
            lt[k * 129 + i] = f2bf(W[(k0 + k) * 1024 + i * 8 + h]);
        }
        __syncthreads();
        short* dst = Wp + (x * 8 + h) * 16384;
        #pragma unroll
        for (int pp = 0; pp < 4; ++pp) {
            const int i  = pp * 32 + (t >> 3);
            const int kk = (t & 7) * 4;
            short4 v;
            v.x = lt[(kk + 0) * 129 + i]; v.y = lt[(kk + 1) * 129 + i];
            v.z = lt[(kk + 2) * 129 + i]; v.w = lt[(kk + 3) * 129 + i];
            *(short4*)&dst[i * 128 + k0 + kk] = v;
        }
    } else {
        const int b2 = b - 96, h = b2 >> 2, c0 = (b2 & 3) * 32;
        #pragma unroll 4
        for (int rr = 0; rr < 16; ++rr) {
            const int i = rr * 8 + (t >> 5);
            const int c = t & 31;
            lt[i * 33 + c] = f2bf(Wout[(i * 8 + h) * 128 + c0 + c]);
        }
        __syncthreads();
        short* dst = Wout_pt + h * 16384;
        #pragma unroll
        for (int pp = 0; pp < 4; ++pp) {
            const int c  = pp * 8 + (t >> 5);
            const int i0 = (t & 31) * 4;
            short4 v;
            v.x = lt[(i0 + 0) * 33 + c]; v.y = lt[(i0 + 1) * 33 + c];
            v.z = lt[(i0 + 2) * 33 + c]; v.w = lt[(i0 + 3) * 33 + c];
            *(short4*)&dst[(c0 + c) * 128 + i0] = v;
        }
    }
}

// ---------------- attn4 ----------------
// LDS zones (shorts): QT[0..4095] Qt[pl][i][p] (persist)
//                     KT[4096..8191] Kt[pl][j][p] (persist)
//                     QN[8192..12287] / KN[12288..16383]: stats, then P bufs
//                     VS[16384..20479]: V natural, then CTX
#define QT   0
#define KT   4096
#define QN   8192
#define KN   12288
#define VS   16384
#define CTXo 16384

__global__ __launch_bounds__(256, 4) void attn4(
    const float* __restrict__ emb,      // [4096][128] fp32
    const short* __restrict__ Wp,       // [3][8][128 i][128 k]
    const short* __restrict__ Wout_pt,  // [8][128 col][128 i]
    float* __restrict__ part)           // [8][4096][128] fp32 partials
{
    __shared__ short lds[20480];        // 40 KB
    const int bid = blockIdx.x;         // 0..1023
    const int pg  = bid >> 3;           // patch group of 4
    const int h   = bid & 7;            // head
    const int t   = threadIdx.x;
    const int w    = t >> 6;            // wave 0..3 (owns patch pl = w)
    const int lane = t & 63;
    const int m16  = lane & 15;
    const int quad = lane >> 4;
    const int q8   = quad * 8;

    // ================= QKV: (32x128) @ W_h (128x128) x3 =================
    {
        bfrag a[2][4];
        #pragma unroll
        for (int tm = 0; tm < 2; ++tm)
            #pragma unroll
            for (int ks = 0; ks < 4; ++ks) {
                const float* er = emb + (size_t)(pg*32 + tm*16 + m16) * 128 + ks*32 + q8;
                const float4 x0 = *(const float4*)er;
                const float4 x1 = *(const float4*)(er + 4);
                bfrag f;
                f[0]=f2bf(x0.x); f[1]=f2bf(x0.y); f[2]=f2bf(x0.z); f[3]=f2bf(x0.w);
                f[4]=f2bf(x1.x); f[5]=f2bf(x1.y); f[6]=f2bf(x1.z); f[7]=f2bf(x1.w);
                a[tm][ks] = f;
            }

        #pragma unroll
        for (int tt = 0; tt < 6; ++tt) {
            const int nt = w * 6 + tt;            // 0..23 = {q,k,v} x 8 i-tiles
            const int x  = nt >> 3;
            const int i0 = (nt & 7) * 16;
            const short* Wb = Wp + ((x*8 + h)*128 + i0 + m16) * 128;
            bfrag bb[4];
            #pragma unroll
            for (int ks = 0; ks < 4; ++ks)
                bb[ks] = *(const bfrag*)&Wb[ks*32 + q8];
            f32x4 c0 = {0.f,0.f,0.f,0.f}, c1 = {0.f,0.f,0.f,0.f};
            #pragma unroll
            for (int ks = 0; ks < 4; ++ks) {
                c0 = __builtin_amdgcn_mfma_f32_16x16x32_bf16(a[0][ks], bb[ks], c0, 0,0,0);
                c1 = __builtin_amdgcn_mfma_f32_16x16x32_bf16(a[1][ks], bb[ks], c1, 0,0,0);
            }
            #pragma unroll
            for (int tm = 0; tm < 2; ++tm) {
                const f32x4 cc = tm ? c1 : c0;
                const int mrow0 = tm*16 + quad*4;     // 4 consecutive tokens
                const int pl = mrow0 >> 3;            // local patch
                const int p0 = mrow0 & 7;             // 0 or 4
                const int col = i0 + m16;
                if (x == 0) {
                    short4 v;
                    v.x = f2bf(cc[0]); v.y = f2bf(cc[1]);
                    v.z = f2bf(cc[2]); v.w = f2bf(cc[3]);
                    *(short4*)&lds[QT + pl*1024 + col*8 + p0] = v;   // Qt[i][p]
                    #pragma unroll
                    for (int r = 0; r < 4; ++r)                      // Qn[p][i]
                        lds[QN + pl*1024 + (p0 + r)*128 + col] = f2bf(cc[r]);
                } else if (x == 1) {
                    short4 v;
                    v.x = f2bf(cc[0]); v.y = f2bf(cc[1]);
                    v.z = f2bf(cc[2]); v.w = f2bf(cc[3]);
                    *(short4*)&lds[KT + pl*1024 + col*8 + p0] = v;   // Kt[j][p]
                    #pragma unroll
                    for (int r = 0; r < 4; ++r)                      // Kn[p][j]
                        lds[KN + pl*1024 + (p0 + r)*128 + col] = f2bf(cc[r]);
                } else {
                    #pragma unroll
                    for (int r = 0; r < 4; ++r)                      // Vs[p][j]
                        lds[VS + pl*1024 + (p0 + r)*128 + col] = f2bf(cc[r]);
                }
            }
        }
    }
    __syncthreads();

    // ===== stats via Grams: sum(S)=sQ.sK, sum(S^2)=tr((QQ^T)(KK^T)) =====
    float rs2, nbias;
    {
        bfrag gq[4], gk[4], gs[4], ones;
        #pragma unroll
        for (int j = 0; j < 8; ++j) ones[j] = (short)0x3F80;   // bf16 1.0
        #pragma unroll
        for (int ks = 0; ks < 4; ++ks) {
            gq[ks] = (m16 < 8) ? *(const bfrag*)&lds[QN + w*1024 + m16*128 + ks*32 + q8] : bzero();
            gk[ks] = (m16 < 8) ? *(const bfrag*)&lds[KN + w*1024 + m16*128 + ks*32 + q8] : bzero();
            gs[ks] = (m16 < 8) ? *(const bfrag*)&lds[QN + w*1024 + m16*128 + ks*32 + q8]
                               : *(const bfrag*)&lds[KN + w*1024 + (m16 - 8)*128 + ks*32 + q8];
        }
        f32x4 cg = {0.f,0.f,0.f,0.f}, ch = {0.f,0.f,0.f,0.f}, cs = {0.f,0.f,0.f,0.f};
        #pragma unroll
        for (int ks = 0; ks < 4; ++ks) {
            cg = __builtin_amdgcn_mfma_f32_16x16x32_bf16(gq[ks], gq[ks], cg, 0,0,0);
            ch = __builtin_amdgcn_mfma_f32_16x16x32_bf16(gk[ks], gk[ks], ch, 0,0,0);
            cs = __builtin_amdgcn_mfma_f32_16x16x32_bf16(gs[ks], ones,  cs, 0,0,0);
        }
        float gh = 0.f, sp = 0.f;
        #pragma unroll
        for (int r = 0; r < 4; ++r) {
            gh = fmaf(cg[r], ch[r], gh);
            sp = fmaf(cs[r], __shfl_xor(cs[r], 32), sp);     // sQ[p]*sK[p]
        }
        sp += __shfl_xor(sp, 16);
        #pragma unroll
        for (int off = 1; off <= 32; off <<= 1)
            gh += __shfl_xor(gh, off);
        const float mean = sp * (1.f / 16384.f);
        const float var  = gh * (1.f / 16384.f) - mean * mean;
        rs2   = rsqrtf(var + 1e-5f) * 1.44269504f;           // fold log2(e)
        nbias = -mean * rs2;
    }

    // ===== hoist K-transposed and V fragments (QN/KN/VS die after barrier) ====
    bfrag bs[8], av[4];
    #pragma unroll
    for (int nt = 0; nt < 8; ++nt)
        bs[nt] = (quad == 0) ? *(const bfrag*)&lds[KT + w*1024 + (nt*16 + m16)*8] : bzero();
    #pragma unroll
    for (int ks = 0; ks < 4; ++ks) {
        if (m16 < 8)
            av[ks] = *(const bfrag*)&lds[VS + w*1024 + m16*128 + ks*32 + q8];
        else if (m16 == 8) {                   // ones ROW -> C[8][i] = rowsum_i
            bfrag o;
            #pragma unroll
            for (int j = 0; j < 8; ++j) o[j] = (short)0x3F80;
            av[ks] = o;
        } else
            av[ks] = bzero();
    }
    __syncthreads();   // all waves done with QN/KN/VS -> safe to overlay

    // ===== 8 bands of 16 score rows; P XOR-swizzled; manual pipeline ========
    // P addr(i,j) = i*128 + ((j>>4 ^ (i&7))<<4) + (j&15)
    short* ps = &lds[QN + w*2048];             // 16 x 128 shorts per wave
    f32x4 c[8];
    {
        const bfrag am = (quad == 0) ? *(const bfrag*)&lds[QT + w*1024 + m16*8] : bzero();
        #pragma unroll
        for (int nt = 0; nt < 8; ++nt) {
            f32x4 z = {0.f,0.f,0.f,0.f};
            c[nt] = __builtin_amdgcn_mfma_f32_16x16x32_bf16(am, bs[nt], z, 0,0,0);
        }
    }
    #pragma unroll 1
    for (int mb = 0; mb < 8; ++mb) {
        // exp + swizzled P write (rows quad*4+r, col nt*16+m16)
        #pragma unroll
        for (int nt = 0; nt < 8; ++nt)
            #pragma unroll
            for (int r = 0; r < 4; ++r) {
                const int row = quad*4 + r;
                ps[row*128 + ((nt ^ (row & 7)) << 4) + m16] =
                    f2bf(exp2f(fmaf(c[nt][r], rs2, nbias)));
            }
        // next band's scores issue between P-write and PV-read (latency cover)
        if (mb < 7) {
            const bfrag am = (quad == 0)
                ? *(const bfrag*)&lds[QT + w*1024 + ((mb+1)*16 + m16)*8] : bzero();
            #pragma unroll
            for (int nt = 0; nt < 8; ++nt) {
                f32x4 z = {0.f,0.f,0.f,0.f};
                c[nt] = __builtin_amdgcn_mfma_f32_16x16x32_bf16(am, bs[nt], z, 0,0,0);
            }
        }
        // PV: C[p][i16] = sum_j V[p][j] * P[i][j]   (B-frag = P rows, b128)
        f32x4 cc = {0.f,0.f,0.f,0.f};
        #pragma unroll
        for (int ks = 0; ks < 4; ++ks) {
            const bfrag bp = *(const bfrag*)
                &ps[m16*128 + (((2*ks + (quad >> 1)) ^ (m16 & 7)) << 4) + (quad & 1)*8];
            cc = __builtin_amdgcn_mfma_f32_16x16x32_bf16(av[ks], bp, cc, 0,0,0);
        }
        const float s  = __shfl(cc[0], 32 + m16);   // C[8][i] from quad-2 lanes
        const float is = 1.0f / s;
        if (quad < 2) {
            #pragma unroll
            for (int r = 0; r < 4; ++r)
                lds[CTXo + w*1024 + (quad*4 + r)*128 + mb*16 + m16] = f2bf(cc[r] * is);
        }
    }

    // ===== fused out-GEMM: ctx^T (8x128) @ Wout_h (128x128) -> partials =====
    bfrag ac[4];
    #pragma unroll
    for (int ks = 0; ks < 4; ++ks)
        ac[ks] = (m16 < 8) ? *(const bfrag*)&lds[CTXo + w*1024 + m16*128 + ks*32 + q8]
                           : bzero();
    const short* Wo = Wout_pt + h * 16384;
    float* pb = part + (size_t)h * 524288 + (size_t)(pg*4 + w) * 8 * 128;
    #pragma unroll 1
    for (int nt = 0; nt < 8; ++nt) {
        f32x4 cc = {0.f,0.f,0.f,0.f};
        #pragma unroll
        for (int ks = 0; ks < 4; ++ks) {
            const bfrag wb = *(const bfrag*)&Wo[(nt*16 + m16)*128 + ks*32 + q8];
            cc = __builtin_amdgcn_mfma_f32_16x16x32_bf16(ac[ks], wb, cc, 0,0,0);
        }
        if (quad < 2) {
            #pragma unroll
            for (int r = 0; r < 4; ++r)
                pb[(quad*4 + r)*128 + nt*16 + m16] = cc[r];
        }
    }
}

// ---------------- reduce8: out[orow][col] = sum_h part[h][rowf][col] --------
__global__ __launch_bounds__(256) void reduce8(
    const float* __restrict__ part, float* __restrict__ out)
{
    const int f = blockIdx.x * 256 + threadIdx.x;   // float4 index, 0..131071
    const int rowf = f >> 5, c4 = f & 31;
    const int pat = rowf >> 3, p = rowf & 7;
    const int bb = pat >> 5, rem = pat & 31;
    const int dd = rem >> 4, hh = (rem >> 2) & 3, ww = rem & 3;
    const int p1 = p >> 2, p2 = (p >> 1) & 1, p3 = p & 1;
    const int orow = bb*256 + ((((dd*2 + p1)*4 + hh)*2 + p2)*4 + ww)*2 + p3;
    const f32x4* p4 = (const f32x4*)part;
    f32x4 s = p4[rowf*32 + c4];
    #pragma unroll
    for (int h = 1; h < 8; ++h)
        s += p4[h*131072 + rowf*32 + c4];
    ((f32x4*)out)[orow*32 + c4] = s;
}

extern "C" void kernel_launch(void* const* d_in, const int* in_sizes, int n_in,
                              void* d_out, int out_size, void* d_ws, size_t ws_size,
                              hipStream_t stream) {
    const float* emb  = (const float*)d_in[0];   // (512, 8, 128)
    const float* Wq   = (const float*)d_in[1];   // (128, 1024)
    const float* Wk   = (const float*)d_in[2];
    const float* Wv   = (const float*)d_in[3];
    const float* Wout = (const float*)d_in[4];   // (1024, 128)
    float* out = (float*)d_out;                  // 524288 floats

    float* part    = (float*)d_ws;                         // 16 MB
    short* Wp      = (short*)((char*)d_ws + 16777216);     // 768 KB
    short* Wout_pt = Wp + 393216;                          // 256 KB

    convertW<<<128, 256, 0, stream>>>(Wq, Wk, Wv, Wout, Wp, Wout_pt);
    attn4<<<1024, 256, 0, stream>>>(emb, Wp, Wout_pt, part);
    reduce8<<<512, 256, 0, stream>>>(part, out);
}